// Round 12
// baseline (775.735 us; speedup 1.0000x reference)
//
#include <hip/hip_runtime.h>

typedef __bf16 bf16_t;
typedef __bf16 bf16x8 __attribute__((ext_vector_type(8)));
typedef float f32x4 __attribute__((ext_vector_type(4)));

#define MFMA(a, b, c) __builtin_amdgcn_mfma_f32_16x16x32_bf16((a), (b), (c), 0, 0, 0)

#define E_ROWS 640000
#define BM 128

static __device__ __forceinline__ bf16x8 cvt8(float4 a, float4 b) {
  bf16x8 r;
  r[0] = (bf16_t)a.x; r[1] = (bf16_t)a.y; r[2] = (bf16_t)a.z; r[3] = (bf16_t)a.w;
  r[4] = (bf16_t)b.x; r[5] = (bf16_t)b.y; r[6] = (bf16_t)b.z; r[7] = (bf16_t)b.w;
  return r;
}

static __device__ __forceinline__ unsigned int pk2(float a, float b) {
  unsigned short ua = __builtin_bit_cast(unsigned short, (bf16_t)a);
  unsigned short ub = __builtin_bit_cast(unsigned short, (bf16_t)b);
  return ((unsigned int)ub << 16) | ua;
}

// async 16B global -> LDS DMA (dest = wave-uniform base + lane*16, no VGPR round-trip)
static __device__ __forceinline__ void gload_lds16(const void* g, void* l) {
  __builtin_amdgcn_global_load_lds(
      (const __attribute__((address_space(1))) unsigned int*)g,
      (__attribute__((address_space(3))) unsigned int*)l, 16, 0, 0);
}

// Fragment-ordered weights in ws (table chunk = frag*64 + lane, 16B each):
//   Wm1: frags 0..63 (chunks 0..4095)      Wm2: frags 64..95  (4096..6143)
//   Wu1: frags 96..159 (6144..10239)       Wu2: frags 160..191 (10240..12287)
// chunk holds 8 bf16: W[k][n], k = 32*ks + 8*(lane>>4) + j, n = 16*nb + (lane&15).
__global__ __launch_bounds__(256) void prep_weights(
    const float* __restrict__ Wm1, const float* __restrict__ Wm2,
    const float* __restrict__ Wu1, const float* __restrict__ Wu2,
    bf16_t* __restrict__ wt) {
  int c = blockIdx.x * 256 + threadIdx.x;  // 12288 chunks of 16B
  if (c >= 12288) return;
  int lane = c & 63, f = c >> 6;
  const float* W; int base;
  if (f < 64)       { W = Wm1; base = 0;   }
  else if (f < 96)  { W = Wm2; base = 64;  }
  else if (f < 160) { W = Wu1; base = 96;  }
  else              { W = Wu2; base = 160; }
  int fl = f - base;
  int ks = fl >> 3, nb = fl & 7;
  int k0 = 32 * ks + 8 * (lane >> 4);
  int n  = 16 * nb + (lane & 15);
  bf16x8 v;
  #pragma unroll
  for (int j = 0; j < 8; ++j) v[j] = (bf16_t)W[(size_t)(k0 + j) * 128 + n];
  ((bf16x8*)wt)[c] = v;
}

// stage 32KB (32 frags = 2048 chunks) from table chunk base tc0 into LDS region
#define STAGE32(dstBase, tc0) { \
  _Pragma("unroll") \
  for (int i_ = 0; i_ < 8; ++i_) \
    gload_lds16((const char*)wt + ((size_t)((tc0) + i_ * 256 + wave * 64 + lane)) * 16, \
                (dstBase) + (i_ * 256 + wave * 64) * 16); }

// 8 W-frags (one ks) from LDS region: per-lane 16B ds_read_b128, conflict-free
#define LDW8(s, base, fl0) \
  s##0 = *(const bf16x8*)((base) + ((fl0) + 0) * 1024 + lane * 16); \
  s##1 = *(const bf16x8*)((base) + ((fl0) + 1) * 1024 + lane * 16); \
  s##2 = *(const bf16x8*)((base) + ((fl0) + 2) * 1024 + lane * 16); \
  s##3 = *(const bf16x8*)((base) + ((fl0) + 3) * 1024 + lane * 16); \
  s##4 = *(const bf16x8*)((base) + ((fl0) + 4) * 1024 + lane * 16); \
  s##5 = *(const bf16x8*)((base) + ((fl0) + 5) * 1024 + lane * 16); \
  s##6 = *(const bf16x8*)((base) + ((fl0) + 6) * 1024 + lane * 16); \
  s##7 = *(const bf16x8*)((base) + ((fl0) + 7) * 1024 + lane * 16);

#define ROUND(s, x0, x1) \
  acc00 = MFMA(s##0, x0, acc00); acc10 = MFMA(s##0, x1, acc10); \
  acc01 = MFMA(s##1, x0, acc01); acc11 = MFMA(s##1, x1, acc11); \
  acc02 = MFMA(s##2, x0, acc02); acc12 = MFMA(s##2, x1, acc12); \
  acc03 = MFMA(s##3, x0, acc03); acc13 = MFMA(s##3, x1, acc13); \
  acc04 = MFMA(s##4, x0, acc04); acc14 = MFMA(s##4, x1, acc14); \
  acc05 = MFMA(s##5, x0, acc05); acc15 = MFMA(s##5, x1, acc15); \
  acc06 = MFMA(s##6, x0, acc06); acc16 = MFMA(s##6, x1, acc16); \
  acc07 = MFMA(s##7, x0, acc07); acc17 = MFMA(s##7, x1, acc17);

// biases from GLOBAL (2KB total, L2-hot across all blocks; transient regs)
#define ACCINIT(bp) { const float* bp_ = (bp) + g * 4; float4 q; \
  q = *(const float4*)(bp_ +   0); acc00 = (f32x4){q.x,q.y,q.z,q.w}; acc10 = acc00; \
  q = *(const float4*)(bp_ +  16); acc01 = (f32x4){q.x,q.y,q.z,q.w}; acc11 = acc01; \
  q = *(const float4*)(bp_ +  32); acc02 = (f32x4){q.x,q.y,q.z,q.w}; acc12 = acc02; \
  q = *(const float4*)(bp_ +  48); acc03 = (f32x4){q.x,q.y,q.z,q.w}; acc13 = acc03; \
  q = *(const float4*)(bp_ +  64); acc04 = (f32x4){q.x,q.y,q.z,q.w}; acc14 = acc04; \
  q = *(const float4*)(bp_ +  80); acc05 = (f32x4){q.x,q.y,q.z,q.w}; acc15 = acc05; \
  q = *(const float4*)(bp_ +  96); acc06 = (f32x4){q.x,q.y,q.z,q.w}; acc16 = acc06; \
  q = *(const float4*)(bp_ + 112); acc07 = (f32x4){q.x,q.y,q.z,q.w}; acc17 = acc07; }

// repack: D holds h[rowbase+16*mt+c][16*nb+4*g+e]; scatter so a later 16B read
// at ((mt*4+ks)*64+lane)*16 yields the next GEMM's B-frag.
#define RPK(av, mt, nb, R) { \
  f32x4 v = av; \
  float e0 = v[0], e1 = v[1], e2 = v[2], e3 = v[3]; \
  if (R) { e0 = fmaxf(e0, 0.f); e1 = fmaxf(e1, 0.f); \
           e2 = fmaxf(e2, 0.f); e3 = fmaxf(e3, 0.f); } \
  uint2 w; w.x = pk2(e0, e1); w.y = pk2(e2, e3); \
  int dl = c + 16 * (2 * ((nb) & 1) + (g >> 1)); \
  *(uint2*)(myrep + (((mt) * 4 + ((nb) >> 1)) * 64 + dl) * 16 + (g & 1) * 8) = w; }

#define RPK_ALL(R) \
  RPK(acc00, 0, 0, R) RPK(acc01, 0, 1, R) RPK(acc02, 0, 2, R) RPK(acc03, 0, 3, R) \
  RPK(acc04, 0, 4, R) RPK(acc05, 0, 5, R) RPK(acc06, 0, 6, R) RPK(acc07, 0, 7, R) \
  RPK(acc10, 1, 0, R) RPK(acc11, 1, 1, R) RPK(acc12, 1, 2, R) RPK(acc13, 1, 3, R) \
  RPK(acc14, 1, 4, R) RPK(acc15, 1, 5, R) RPK(acc16, 1, 6, R) RPK(acc17, 1, 7, R)

#define WAITLDS asm volatile("s_waitcnt lgkmcnt(0)" ::: "memory");
#define VMCNT0  asm volatile("s_waitcnt vmcnt(0)" ::: "memory");

#define RDB(d00, d01, d02, d03, d10, d11, d12, d13) \
  d00 = *(const bf16x8*)(myrep + (0 * 64 + lane) * 16); \
  d01 = *(const bf16x8*)(myrep + (1 * 64 + lane) * 16); \
  d02 = *(const bf16x8*)(myrep + (2 * 64 + lane) * 16); \
  d03 = *(const bf16x8*)(myrep + (3 * 64 + lane) * 16); \
  d10 = *(const bf16x8*)(myrep + (4 * 64 + lane) * 16); \
  d11 = *(const bf16x8*)(myrep + (5 * 64 + lane) * 16); \
  d12 = *(const bf16x8*)(myrep + (6 * 64 + lane) * 16); \
  d13 = *(const bf16x8*)(myrep + (7 * 64 + lane) * 16);

#define LOADX(d0, d1, basep, kk) { \
  float4 a0 = *(const float4*)((basep) + r0 + (kk) * 32); \
  float4 a1 = *(const float4*)((basep) + r0 + (kk) * 32 + 4); \
  float4 b0 = *(const float4*)((basep) + r1 + (kk) * 32); \
  float4 b1 = *(const float4*)((basep) + r1 + (kk) * 32 + 4); \
  d0 = cvt8(a0, a1); d1 = cvt8(b0, b1); }

#define ST(av, mt, nb) { f32x4 v = av; \
  *(float4*)(out + (rowbase + (mt) * 16 + c) * 128 + (nb) * 16 + g * 4) = \
      (float4){v[0], v[1], v[2], v[3]}; }

// LDS map: WA 0..32K | WB 32K..64K == 65536 B.
// Register budget: arch ~176 + 64 acc (unified) = 240 <= 256 -> 2 waves/SIMD.
// Single-buffered W frags (wa only): -32 arch regs vs R11; __launch_bounds__
// (256,2) holds the allocator to the 256-unified budget.
__global__ __launch_bounds__(256, 2) void fused_mp(
    const float* __restrict__ hself, const float* __restrict__ hother,
    const bf16_t* __restrict__ wt,
    const float* __restrict__ bm1, const float* __restrict__ bm2,
    const float* __restrict__ bu1, const float* __restrict__ bu2,
    float* __restrict__ out) {
  __shared__ char smem[65536];

  const int tid = threadIdx.x;
  const int lane = tid & 63;
  const int wave = tid >> 6;
  const int c = lane & 15;
  const int g = lane >> 4;

  char* WA = smem;
  char* WB = smem + 32768;
  char* myrep = smem + wave * 8192;  // conv region aliased inside WA

  const size_t rowbase = (size_t)blockIdx.x * BM + wave * 32;
  const size_t r0 = (rowbase + c) * 128 + g * 8;
  const size_t r1 = (rowbase + 16 + c) * 128 + g * 8;

  // ---- prologue: x loads (hself), async W DMA, x loads (hother) ----
  bf16x8 hs00, hs01, hs02, hs03, hs10, hs11, hs12, hs13;
  bf16x8 ho00, ho01, ho02, ho03, ho10, ho11, ho12, ho13;
  LOADX(hs00, hs10, hself, 0)
  LOADX(hs01, hs11, hself, 1)
  LOADX(hs02, hs12, hself, 2)
  LOADX(hs03, hs13, hself, 3)
  STAGE32(WA, 0)      // Wm1 ks0-3
  STAGE32(WB, 2048)   // Wm1 ks4-7
  LOADX(ho00, ho10, hother, 0)
  LOADX(ho01, ho11, hother, 1)
  LOADX(ho02, ho12, hother, 2)
  LOADX(ho03, ho13, hother, 3)
  VMCNT0
  __syncthreads();  // B0: Wm1 staged

  f32x4 acc00, acc01, acc02, acc03, acc04, acc05, acc06, acc07;
  f32x4 acc10, acc11, acc12, acc13, acc14, acc15, acc16, acc17;
  bf16x8 wa0, wa1, wa2, wa3, wa4, wa5, wa6, wa7;

  // ============ GEMM1: h1^T = Wm1^T [hs|ho]^T  (+bm1, relu) ============
  ACCINIT(bm1)
  LDW8(wa, WA, 0)   ROUND(wa, hs00, hs10)
  LDW8(wa, WA, 8)   ROUND(wa, hs01, hs11)
  LDW8(wa, WA, 16)  ROUND(wa, hs02, hs12)
  LDW8(wa, WA, 24)  ROUND(wa, hs03, hs13)
  LDW8(wa, WB, 0)   ROUND(wa, ho00, ho10)
  LDW8(wa, WB, 8)   ROUND(wa, ho01, ho11)
  LDW8(wa, WB, 16)  ROUND(wa, ho02, ho12)
  LDW8(wa, WB, 24)  ROUND(wa, ho03, ho13)
  __syncthreads();  // B1: all GEMM1 reads done

  STAGE32(WB, 4096)  // Wm2 -> WB (async, overlaps repack)
  RPK_ALL(true)      // conv -> WA (wave-private)
  WAITLDS
  bf16x8 t00, t01, t02, t03, t10, t11, t12, t13;
  RDB(t00, t01, t02, t03, t10, t11, t12, t13)
  VMCNT0
  __syncthreads();  // B2: Wm2 staged everywhere

  // ============ GEMM2: msg^T = Wm2^T h1^T  (+bm2) ============
  ACCINIT(bm2)
  LDW8(wa, WB, 0)   ROUND(wa, t00, t10)
  LDW8(wa, WB, 8)   ROUND(wa, t01, t11)
  LDW8(wa, WB, 16)  ROUND(wa, t02, t12)
  LDW8(wa, WB, 24)  ROUND(wa, t03, t13)
  __syncthreads();  // B3: GEMM2 reads done

  STAGE32(WB, 6144)  // Wu1 ks0-3 (hs part) -> WB
  RPK_ALL(false)     // msg conv -> WA
  WAITLDS
  bf16x8 m00, m01, m02, m03, m10, m11, m12, m13;
  RDB(m00, m01, m02, m03, m10, m11, m12, m13)
  __syncthreads();  // B4: conv consumed by all waves; WA free

  STAGE32(WA, 8192)  // Wu1 ks4-7 (msg part) -> WA
  VMCNT0
  __syncthreads();  // B5: Wu1 fully staged everywhere

  // ============ GEMM3: h2^T = Wu1^T [hs|msg]^T  (+bu1, relu) ============
  ACCINIT(bu1)
  LDW8(wa, WB, 0)   ROUND(wa, hs00, hs10)
  LDW8(wa, WB, 8)   ROUND(wa, hs01, hs11)
  LDW8(wa, WB, 16)  ROUND(wa, hs02, hs12)
  LDW8(wa, WB, 24)  ROUND(wa, hs03, hs13)
  LDW8(wa, WA, 0)   ROUND(wa, m00, m10)
  LDW8(wa, WA, 8)   ROUND(wa, m01, m11)
  LDW8(wa, WA, 16)  ROUND(wa, m02, m12)
  LDW8(wa, WA, 24)  ROUND(wa, m03, m13)
  __syncthreads();  // B6: GEMM3 reads done

  STAGE32(WB, 10240)  // Wu2 -> WB
  RPK_ALL(true)       // h2 conv -> WA
  WAITLDS
  RDB(t00, t01, t02, t03, t10, t11, t12, t13)
  VMCNT0
  __syncthreads();  // B7: Wu2 staged everywhere

  // ============ GEMM4: out^T = Wu2^T h2^T  (+bu2) ============
  ACCINIT(bu2)
  LDW8(wa, WB, 0)   ROUND(wa, t00, t10)
  LDW8(wa, WB, 8)   ROUND(wa, t01, t11)
  LDW8(wa, WB, 16)  ROUND(wa, t02, t12)
  LDW8(wa, WB, 24)  ROUND(wa, t03, t13)

  ST(acc00, 0, 0) ST(acc01, 0, 1) ST(acc02, 0, 2) ST(acc03, 0, 3)
  ST(acc04, 0, 4) ST(acc05, 0, 5) ST(acc06, 0, 6) ST(acc07, 0, 7)
  ST(acc10, 1, 0) ST(acc11, 1, 1) ST(acc12, 1, 2) ST(acc13, 1, 3)
  ST(acc14, 1, 4) ST(acc15, 1, 5) ST(acc16, 1, 6) ST(acc17, 1, 7)
}

extern "C" void kernel_launch(void* const* d_in, const int* in_sizes, int n_in,
                              void* d_out, int out_size, void* d_ws, size_t ws_size,
                              hipStream_t stream) {
  const float* hself  = (const float*)d_in[0];
  const float* hother = (const float*)d_in[1];
  const float* Wm1 = (const float*)d_in[2];
  const float* bm1 = (const float*)d_in[3];
  const float* Wm2 = (const float*)d_in[4];
  const float* bm2 = (const float*)d_in[5];
  const float* Wu1 = (const float*)d_in[6];
  const float* bu1 = (const float*)d_in[7];
  const float* Wu2 = (const float*)d_in[8];
  const float* bu2 = (const float*)d_in[9];
  float* out = (float*)d_out;
  bf16_t* wt = (bf16_t*)d_ws;  // 196608 B of fragment-ordered bf16 weights

  prep_weights<<<48, 256, 0, stream>>>(Wm1, Wm2, Wu1, Wu2, wt);
  fused_mp<<<E_ROWS / BM, 256, 0, stream>>>(hself, hother, wt,
                                            bm1, bm2, bu1, bu2, out);
}

// Round 13
// 360.204 us; speedup vs baseline: 2.1536x; 2.1536x over previous
//
#include <hip/hip_runtime.h>

typedef __bf16 bf16_t;
typedef __bf16 bf16x8 __attribute__((ext_vector_type(8)));
typedef float f32x4 __attribute__((ext_vector_type(4)));

#define MFMA(a, b, c) __builtin_amdgcn_mfma_f32_16x16x32_bf16((a), (b), (c), 0, 0, 0)

#define E_ROWS 640000
#define BM 128

static __device__ __forceinline__ bf16x8 cvt8(float4 a, float4 b) {
  bf16x8 r;
  r[0] = (bf16_t)a.x; r[1] = (bf16_t)a.y; r[2] = (bf16_t)a.z; r[3] = (bf16_t)a.w;
  r[4] = (bf16_t)b.x; r[5] = (bf16_t)b.y; r[6] = (bf16_t)b.z; r[7] = (bf16_t)b.w;
  return r;
}

static __device__ __forceinline__ unsigned int pk2(float a, float b) {
  unsigned short ua = __builtin_bit_cast(unsigned short, (bf16_t)a);
  unsigned short ub = __builtin_bit_cast(unsigned short, (bf16_t)b);
  return ((unsigned int)ub << 16) | ua;
}

// async 16B global -> LDS DMA (dest = wave-uniform base + lane*16, no VGPR round-trip)
static __device__ __forceinline__ void gload_lds16(const void* g, void* l) {
  __builtin_amdgcn_global_load_lds(
      (const __attribute__((address_space(1))) unsigned int*)g,
      (__attribute__((address_space(3))) unsigned int*)l, 16, 0, 0);
}

// Fragment-ordered weights in ws (table chunk = frag*64 + lane, 16B each):
//   Wm1: frags 0..63 (chunks 0..4095)      Wm2: frags 64..95  (4096..6143)
//   Wu1: frags 96..159 (6144..10239)       Wu2: frags 160..191 (10240..12287)
// chunk holds 8 bf16: W[k][n], k = 32*ks + 8*(lane>>4) + j, n = 16*nb + (lane&15).
__global__ __launch_bounds__(256) void prep_weights(
    const float* __restrict__ Wm1, const float* __restrict__ Wm2,
    const float* __restrict__ Wu1, const float* __restrict__ Wu2,
    bf16_t* __restrict__ wt) {
  int c = blockIdx.x * 256 + threadIdx.x;  // 12288 chunks of 16B
  if (c >= 12288) return;
  int lane = c & 63, f = c >> 6;
  const float* W; int base;
  if (f < 64)       { W = Wm1; base = 0;   }
  else if (f < 96)  { W = Wm2; base = 64;  }
  else if (f < 160) { W = Wu1; base = 96;  }
  else              { W = Wu2; base = 160; }
  int fl = f - base;
  int ks = fl >> 3, nb = fl & 7;
  int k0 = 32 * ks + 8 * (lane >> 4);
  int n  = 16 * nb + (lane & 15);
  bf16x8 v;
  #pragma unroll
  for (int j = 0; j < 8; ++j) v[j] = (bf16_t)W[(size_t)(k0 + j) * 128 + n];
  ((bf16x8*)wt)[c] = v;
}

// stage 32KB (32 frags = 2048 chunks) from table chunk base tc0 into LDS region
#define STAGE32(dstBase, tc0) { \
  _Pragma("unroll") \
  for (int i_ = 0; i_ < 8; ++i_) \
    gload_lds16((const char*)wt + ((size_t)((tc0) + i_ * 256 + wave * 64 + lane)) * 16, \
                (dstBase) + (i_ * 256 + wave * 64) * 16); }

// 8 W-frags (one ks) from LDS region: per-lane 16B ds_read_b128, conflict-free
#define LDW8(s, base, fl0) \
  s##0 = *(const bf16x8*)((base) + ((fl0) + 0) * 1024 + lane * 16); \
  s##1 = *(const bf16x8*)((base) + ((fl0) + 1) * 1024 + lane * 16); \
  s##2 = *(const bf16x8*)((base) + ((fl0) + 2) * 1024 + lane * 16); \
  s##3 = *(const bf16x8*)((base) + ((fl0) + 3) * 1024 + lane * 16); \
  s##4 = *(const bf16x8*)((base) + ((fl0) + 4) * 1024 + lane * 16); \
  s##5 = *(const bf16x8*)((base) + ((fl0) + 5) * 1024 + lane * 16); \
  s##6 = *(const bf16x8*)((base) + ((fl0) + 6) * 1024 + lane * 16); \
  s##7 = *(const bf16x8*)((base) + ((fl0) + 7) * 1024 + lane * 16);

#define ROUND(s, x0, x1) \
  acc00 = MFMA(s##0, x0, acc00); acc10 = MFMA(s##0, x1, acc10); \
  acc01 = MFMA(s##1, x0, acc01); acc11 = MFMA(s##1, x1, acc11); \
  acc02 = MFMA(s##2, x0, acc02); acc12 = MFMA(s##2, x1, acc12); \
  acc03 = MFMA(s##3, x0, acc03); acc13 = MFMA(s##3, x1, acc13); \
  acc04 = MFMA(s##4, x0, acc04); acc14 = MFMA(s##4, x1, acc14); \
  acc05 = MFMA(s##5, x0, acc05); acc15 = MFMA(s##5, x1, acc15); \
  acc06 = MFMA(s##6, x0, acc06); acc16 = MFMA(s##6, x1, acc16); \
  acc07 = MFMA(s##7, x0, acc07); acc17 = MFMA(s##7, x1, acc17);

// biases from GLOBAL (2KB total, L2-hot across all blocks; transient regs)
#define ACCINIT(bp) { const float* bp_ = (bp) + g * 4; float4 q; \
  q = *(const float4*)(bp_ +   0); acc00 = (f32x4){q.x,q.y,q.z,q.w}; acc10 = acc00; \
  q = *(const float4*)(bp_ +  16); acc01 = (f32x4){q.x,q.y,q.z,q.w}; acc11 = acc01; \
  q = *(const float4*)(bp_ +  32); acc02 = (f32x4){q.x,q.y,q.z,q.w}; acc12 = acc02; \
  q = *(const float4*)(bp_ +  48); acc03 = (f32x4){q.x,q.y,q.z,q.w}; acc13 = acc03; \
  q = *(const float4*)(bp_ +  64); acc04 = (f32x4){q.x,q.y,q.z,q.w}; acc14 = acc04; \
  q = *(const float4*)(bp_ +  80); acc05 = (f32x4){q.x,q.y,q.z,q.w}; acc15 = acc05; \
  q = *(const float4*)(bp_ +  96); acc06 = (f32x4){q.x,q.y,q.z,q.w}; acc16 = acc06; \
  q = *(const float4*)(bp_ + 112); acc07 = (f32x4){q.x,q.y,q.z,q.w}; acc17 = acc07; }

// repack: D holds h[rowbase+16*mt+c][16*nb+4*g+e]; scatter so a later 16B read
// at ((mt*4+ks)*64+lane)*16 yields the next GEMM's B-frag.
#define RPK(av, mt, nb, R) { \
  f32x4 v = av; \
  float e0 = v[0], e1 = v[1], e2 = v[2], e3 = v[3]; \
  if (R) { e0 = fmaxf(e0, 0.f); e1 = fmaxf(e1, 0.f); \
           e2 = fmaxf(e2, 0.f); e3 = fmaxf(e3, 0.f); } \
  uint2 w; w.x = pk2(e0, e1); w.y = pk2(e2, e3); \
  int dl = c + 16 * (2 * ((nb) & 1) + (g >> 1)); \
  *(uint2*)(myrep + (((mt) * 4 + ((nb) >> 1)) * 64 + dl) * 16 + (g & 1) * 8) = w; }

#define RPK_ALL(R) \
  RPK(acc00, 0, 0, R) RPK(acc01, 0, 1, R) RPK(acc02, 0, 2, R) RPK(acc03, 0, 3, R) \
  RPK(acc04, 0, 4, R) RPK(acc05, 0, 5, R) RPK(acc06, 0, 6, R) RPK(acc07, 0, 7, R) \
  RPK(acc10, 1, 0, R) RPK(acc11, 1, 1, R) RPK(acc12, 1, 2, R) RPK(acc13, 1, 3, R) \
  RPK(acc14, 1, 4, R) RPK(acc15, 1, 5, R) RPK(acc16, 1, 6, R) RPK(acc17, 1, 7, R)

#define WAITLDS asm volatile("s_waitcnt lgkmcnt(0)" ::: "memory");
#define VMCNT0  asm volatile("s_waitcnt vmcnt(0)" ::: "memory");

// read repacked B-frags into the shared x-block
#define RDBX \
  x00 = *(const bf16x8*)(myrep + (0 * 64 + lane) * 16); \
  x01 = *(const bf16x8*)(myrep + (1 * 64 + lane) * 16); \
  x02 = *(const bf16x8*)(myrep + (2 * 64 + lane) * 16); \
  x03 = *(const bf16x8*)(myrep + (3 * 64 + lane) * 16); \
  x10 = *(const bf16x8*)(myrep + (4 * 64 + lane) * 16); \
  x11 = *(const bf16x8*)(myrep + (5 * 64 + lane) * 16); \
  x12 = *(const bf16x8*)(myrep + (6 * 64 + lane) * 16); \
  x13 = *(const bf16x8*)(myrep + (7 * 64 + lane) * 16);

#define LOADX(d0, d1, basep, kk) { \
  float4 a0 = *(const float4*)((basep) + r0 + (kk) * 32); \
  float4 a1 = *(const float4*)((basep) + r0 + (kk) * 32 + 4); \
  float4 b0 = *(const float4*)((basep) + r1 + (kk) * 32); \
  float4 b1 = *(const float4*)((basep) + r1 + (kk) * 32 + 4); \
  d0 = cvt8(a0, a1); d1 = cvt8(b0, b1); }

#define ST(av, mt, nb) { f32x4 v = av; \
  *(float4*)(out + (rowbase + (mt) * 16 + c) * 128 + (nb) * 16 + g * 4) = \
      (float4){v[0], v[1], v[2], v[3]}; }

// LDS map: WA 0..32K | WB 32K..64K == 65536 B.
// Live set: acc 64 (AGPR) + hs 32 + x 32 + wa 32 + addr ~20 => ~180 unified,
// arch ~115-125 -> 2 waves/SIMD NATURALLY (no coercion; R12's forced (256,2)
// spilled to HBM: WRITE 320MB->1.82GB, dur 775). ho/t/m/t2 are temporally
// disjoint -> one shared x-block. hs persists for GEMM3.
__global__ __launch_bounds__(256) void fused_mp(
    const float* __restrict__ hself, const float* __restrict__ hother,
    const bf16_t* __restrict__ wt,
    const float* __restrict__ bm1, const float* __restrict__ bm2,
    const float* __restrict__ bu1, const float* __restrict__ bu2,
    float* __restrict__ out) {
  __shared__ char smem[65536];

  const int tid = threadIdx.x;
  const int lane = tid & 63;
  const int wave = tid >> 6;
  const int c = lane & 15;
  const int g = lane >> 4;

  char* WA = smem;
  char* WB = smem + 32768;
  char* myrep = smem + wave * 8192;  // conv region aliased inside WA

  const size_t rowbase = (size_t)blockIdx.x * BM + wave * 32;
  const size_t r0 = (rowbase + c) * 128 + g * 8;
  const size_t r1 = (rowbase + 16 + c) * 128 + g * 8;

  // ---- prologue: x loads (hself persistent), async W DMA, x-block = hother --
  bf16x8 hs00, hs01, hs02, hs03, hs10, hs11, hs12, hs13;
  bf16x8 x00, x01, x02, x03, x10, x11, x12, x13;
  LOADX(hs00, hs10, hself, 0)
  LOADX(hs01, hs11, hself, 1)
  LOADX(hs02, hs12, hself, 2)
  LOADX(hs03, hs13, hself, 3)
  STAGE32(WA, 0)      // Wm1 ks0-3
  STAGE32(WB, 2048)   // Wm1 ks4-7
  LOADX(x00, x10, hother, 0)
  LOADX(x01, x11, hother, 1)
  LOADX(x02, x12, hother, 2)
  LOADX(x03, x13, hother, 3)
  VMCNT0
  __syncthreads();  // B0: Wm1 staged

  f32x4 acc00, acc01, acc02, acc03, acc04, acc05, acc06, acc07;
  f32x4 acc10, acc11, acc12, acc13, acc14, acc15, acc16, acc17;
  bf16x8 wa0, wa1, wa2, wa3, wa4, wa5, wa6, wa7;

  // ============ GEMM1: h1^T = Wm1^T [hs|ho]^T  (+bm1, relu) ============
  ACCINIT(bm1)
  LDW8(wa, WA, 0)   ROUND(wa, hs00, hs10)
  LDW8(wa, WA, 8)   ROUND(wa, hs01, hs11)
  LDW8(wa, WA, 16)  ROUND(wa, hs02, hs12)
  LDW8(wa, WA, 24)  ROUND(wa, hs03, hs13)
  LDW8(wa, WB, 0)   ROUND(wa, x00, x10)
  LDW8(wa, WB, 8)   ROUND(wa, x01, x11)
  LDW8(wa, WB, 16)  ROUND(wa, x02, x12)
  LDW8(wa, WB, 24)  ROUND(wa, x03, x13)
  __syncthreads();  // B1: all GEMM1 reads done

  STAGE32(WB, 4096)  // Wm2 -> WB (async, overlaps repack)
  RPK_ALL(true)      // conv -> WA (wave-private)
  WAITLDS
  RDBX               // x-block = h1 B-frags
  VMCNT0
  __syncthreads();  // B2: Wm2 staged everywhere

  // ============ GEMM2: msg^T = Wm2^T h1^T  (+bm2) ============
  ACCINIT(bm2)
  LDW8(wa, WB, 0)   ROUND(wa, x00, x10)
  LDW8(wa, WB, 8)   ROUND(wa, x01, x11)
  LDW8(wa, WB, 16)  ROUND(wa, x02, x12)
  LDW8(wa, WB, 24)  ROUND(wa, x03, x13)
  __syncthreads();  // B3: GEMM2 reads done

  STAGE32(WB, 6144)  // Wu1 ks0-3 (hs part) -> WB
  RPK_ALL(false)     // msg conv -> WA
  WAITLDS
  RDBX               // x-block = msg B-frags
  __syncthreads();  // B4: conv consumed by all waves; WA free

  STAGE32(WA, 8192)  // Wu1 ks4-7 (msg part) -> WA
  VMCNT0
  __syncthreads();  // B5: Wu1 fully staged everywhere

  // ============ GEMM3: h2^T = Wu1^T [hs|msg]^T  (+bu1, relu) ============
  ACCINIT(bu1)
  LDW8(wa, WB, 0)   ROUND(wa, hs00, hs10)
  LDW8(wa, WB, 8)   ROUND(wa, hs01, hs11)
  LDW8(wa, WB, 16)  ROUND(wa, hs02, hs12)
  LDW8(wa, WB, 24)  ROUND(wa, hs03, hs13)
  LDW8(wa, WA, 0)   ROUND(wa, x00, x10)
  LDW8(wa, WA, 8)   ROUND(wa, x01, x11)
  LDW8(wa, WA, 16)  ROUND(wa, x02, x12)
  LDW8(wa, WA, 24)  ROUND(wa, x03, x13)
  __syncthreads();  // B6: GEMM3 reads done

  STAGE32(WB, 10240)  // Wu2 -> WB
  RPK_ALL(true)       // h2 conv -> WA
  WAITLDS
  RDBX                // x-block = h2 B-frags
  VMCNT0
  __syncthreads();  // B7: Wu2 staged everywhere

  // ============ GEMM4: out^T = Wu2^T h2^T  (+bu2) ============
  ACCINIT(bu2)
  LDW8(wa, WB, 0)   ROUND(wa, x00, x10)
  LDW8(wa, WB, 8)   ROUND(wa, x01, x11)
  LDW8(wa, WB, 16)  ROUND(wa, x02, x12)
  LDW8(wa, WB, 24)  ROUND(wa, x03, x13)

  ST(acc00, 0, 0) ST(acc01, 0, 1) ST(acc02, 0, 2) ST(acc03, 0, 3)
  ST(acc04, 0, 4) ST(acc05, 0, 5) ST(acc06, 0, 6) ST(acc07, 0, 7)
  ST(acc10, 1, 0) ST(acc11, 1, 1) ST(acc12, 1, 2) ST(acc13, 1, 3)
  ST(acc14, 1, 4) ST(acc15, 1, 5) ST(acc16, 1, 6) ST(acc17, 1, 7)
}

extern "C" void kernel_launch(void* const* d_in, const int* in_sizes, int n_in,
                              void* d_out, int out_size, void* d_ws, size_t ws_size,
                              hipStream_t stream) {
  const float* hself  = (const float*)d_in[0];
  const float* hother = (const float*)d_in[1];
  const float* Wm1 = (const float*)d_in[2];
  const float* bm1 = (const float*)d_in[3];
  const float* Wm2 = (const float*)d_in[4];
  const float* bm2 = (const float*)d_in[5];
  const float* Wu1 = (const float*)d_in[6];
  const float* bu1 = (const float*)d_in[7];
  const float* Wu2 = (const float*)d_in[8];
  const float* bu2 = (const float*)d_in[9];
  float* out = (float*)d_out;
  bf16_t* wt = (bf16_t*)d_ws;  // 196608 B of fragment-ordered bf16 weights

  prep_weights<<<48, 256, 0, stream>>>(Wm1, Wm2, Wu1, Wu2, wt);
  fused_mp<<<E_ROWS / BM, 256, 0, stream>>>(hself, hother, wt,
                                            bm1, bm2, bu1, bu2, out);
}

// Round 14
// 289.150 us; speedup vs baseline: 2.6828x; 1.2457x over previous
//
#include <hip/hip_runtime.h>

typedef __bf16 bf16_t;
typedef __bf16 bf16x8 __attribute__((ext_vector_type(8)));
typedef float f32x4 __attribute__((ext_vector_type(4)));

#define MFMA(a, b, c) __builtin_amdgcn_mfma_f32_16x16x32_bf16((a), (b), (c), 0, 0, 0)

#define E_ROWS 640000
#define BM 256  // rows per block: 8 waves x 32

static __device__ __forceinline__ bf16x8 cvt8(float4 a, float4 b) {
  bf16x8 r;
  r[0] = (bf16_t)a.x; r[1] = (bf16_t)a.y; r[2] = (bf16_t)a.z; r[3] = (bf16_t)a.w;
  r[4] = (bf16_t)b.x; r[5] = (bf16_t)b.y; r[6] = (bf16_t)b.z; r[7] = (bf16_t)b.w;
  return r;
}

static __device__ __forceinline__ unsigned int pk2(float a, float b) {
  unsigned short ua = __builtin_bit_cast(unsigned short, (bf16_t)a);
  unsigned short ub = __builtin_bit_cast(unsigned short, (bf16_t)b);
  return ((unsigned int)ub << 16) | ua;
}

// async 16B global -> LDS DMA (dest = wave-uniform base + lane*16)
static __device__ __forceinline__ void gload_lds16(const void* g, void* l) {
  __builtin_amdgcn_global_load_lds(
      (const __attribute__((address_space(1))) unsigned int*)g,
      (__attribute__((address_space(3))) unsigned int*)l, 16, 0, 0);
}

// Fragment-ordered weights in ws (table chunk = frag*64 + lane, 16B each):
//   Wm1: frags 0..63 (chunks 0..4095)      Wm2: frags 64..95  (4096..6143)
//   Wu1: frags 96..159 (6144..10239)       Wu2: frags 160..191 (10240..12287)
// chunk holds 8 bf16: W[k][n], k = 32*ks + 8*(lane>>4) + j, n = 16*nb + (lane&15).
__global__ __launch_bounds__(256) void prep_weights(
    const float* __restrict__ Wm1, const float* __restrict__ Wm2,
    const float* __restrict__ Wu1, const float* __restrict__ Wu2,
    bf16_t* __restrict__ wt) {
  int c = blockIdx.x * 256 + threadIdx.x;  // 12288 chunks of 16B
  if (c >= 12288) return;
  int lane = c & 63, f = c >> 6;
  const float* W; int base;
  if (f < 64)       { W = Wm1; base = 0;   }
  else if (f < 96)  { W = Wm2; base = 64;  }
  else if (f < 160) { W = Wu1; base = 96;  }
  else              { W = Wu2; base = 160; }
  int fl = f - base;
  int ks = fl >> 3, nb = fl & 7;
  int k0 = 32 * ks + 8 * (lane >> 4);
  int n  = 16 * nb + (lane & 15);
  bf16x8 v;
  #pragma unroll
  for (int j = 0; j < 8; ++j) v[j] = (bf16_t)W[(size_t)(k0 + j) * 128 + n];
  ((bf16x8*)wt)[c] = v;
}

// stage 96KB (6144 chunks) from table base tc0 into LDS 0..98303 (512 threads)
#define STAGE96(tc0) { \
  _Pragma("unroll") \
  for (int i_ = 0; i_ < 12; ++i_) \
    gload_lds16((const char*)wt + ((size_t)((tc0) + i_ * 512 + tid)) * 16, \
                smem + (i_ * 512 + tid) * 16); }

// 8 W-frags (one ks): per-lane 16B ds_read_b128, conflict-free
#define LDW8(s, base, fl0) \
  s##0 = *(const bf16x8*)((base) + ((fl0) + 0) * 1024 + lane * 16); \
  s##1 = *(const bf16x8*)((base) + ((fl0) + 1) * 1024 + lane * 16); \
  s##2 = *(const bf16x8*)((base) + ((fl0) + 2) * 1024 + lane * 16); \
  s##3 = *(const bf16x8*)((base) + ((fl0) + 3) * 1024 + lane * 16); \
  s##4 = *(const bf16x8*)((base) + ((fl0) + 4) * 1024 + lane * 16); \
  s##5 = *(const bf16x8*)((base) + ((fl0) + 5) * 1024 + lane * 16); \
  s##6 = *(const bf16x8*)((base) + ((fl0) + 6) * 1024 + lane * 16); \
  s##7 = *(const bf16x8*)((base) + ((fl0) + 7) * 1024 + lane * 16);

#define ROUND(s, x0, x1) \
  acc00 = MFMA(s##0, x0, acc00); acc10 = MFMA(s##0, x1, acc10); \
  acc01 = MFMA(s##1, x0, acc01); acc11 = MFMA(s##1, x1, acc11); \
  acc02 = MFMA(s##2, x0, acc02); acc12 = MFMA(s##2, x1, acc12); \
  acc03 = MFMA(s##3, x0, acc03); acc13 = MFMA(s##3, x1, acc13); \
  acc04 = MFMA(s##4, x0, acc04); acc14 = MFMA(s##4, x1, acc14); \
  acc05 = MFMA(s##5, x0, acc05); acc15 = MFMA(s##5, x1, acc15); \
  acc06 = MFMA(s##6, x0, acc06); acc16 = MFMA(s##6, x1, acc16); \
  acc07 = MFMA(s##7, x0, acc07); acc17 = MFMA(s##7, x1, acc17);

// biases from GLOBAL (2KB total, L2-hot; transient regs)
#define ACCINIT(bp) { const float* bp_ = (bp) + g * 4; float4 q; \
  q = *(const float4*)(bp_ +   0); acc00 = (f32x4){q.x,q.y,q.z,q.w}; acc10 = acc00; \
  q = *(const float4*)(bp_ +  16); acc01 = (f32x4){q.x,q.y,q.z,q.w}; acc11 = acc01; \
  q = *(const float4*)(bp_ +  32); acc02 = (f32x4){q.x,q.y,q.z,q.w}; acc12 = acc02; \
  q = *(const float4*)(bp_ +  48); acc03 = (f32x4){q.x,q.y,q.z,q.w}; acc13 = acc03; \
  q = *(const float4*)(bp_ +  64); acc04 = (f32x4){q.x,q.y,q.z,q.w}; acc14 = acc04; \
  q = *(const float4*)(bp_ +  80); acc05 = (f32x4){q.x,q.y,q.z,q.w}; acc15 = acc05; \
  q = *(const float4*)(bp_ +  96); acc06 = (f32x4){q.x,q.y,q.z,q.w}; acc16 = acc06; \
  q = *(const float4*)(bp_ + 112); acc07 = (f32x4){q.x,q.y,q.z,q.w}; acc17 = acc07; }

// half-repack (one mt, 4KB/wave): D holds h[row][16nb+4g+e]; scatter so a 16B
// read at (ks*64+lane)*16 yields the next GEMM's B-frag for this mt's rows.
#define RPK_H(av, nb, R) { \
  f32x4 v = av; \
  float e0 = v[0], e1 = v[1], e2 = v[2], e3 = v[3]; \
  if (R) { e0 = fmaxf(e0, 0.f); e1 = fmaxf(e1, 0.f); \
           e2 = fmaxf(e2, 0.f); e3 = fmaxf(e3, 0.f); } \
  uint2 w; w.x = pk2(e0, e1); w.y = pk2(e2, e3); \
  int dl = c + 16 * (2 * ((nb) & 1) + (g >> 1)); \
  *(uint2*)(myrep + (((nb) >> 1) * 64 + dl) * 16 + (g & 1) * 8) = w; }

#define WAITLDS asm volatile("s_waitcnt lgkmcnt(0)" ::: "memory");
#define VMCNT0  asm volatile("s_waitcnt vmcnt(0)" ::: "memory");

// full repack: mt=0 write+read, then mt=1 write+read (wave-local, in-order LDS)
#define REPACK(R) \
  RPK_H(acc00, 0, R) RPK_H(acc01, 1, R) RPK_H(acc02, 2, R) RPK_H(acc03, 3, R) \
  RPK_H(acc04, 4, R) RPK_H(acc05, 5, R) RPK_H(acc06, 6, R) RPK_H(acc07, 7, R) \
  WAITLDS \
  x00 = *(const bf16x8*)(myrep + (0 * 64 + lane) * 16); \
  x01 = *(const bf16x8*)(myrep + (1 * 64 + lane) * 16); \
  x02 = *(const bf16x8*)(myrep + (2 * 64 + lane) * 16); \
  x03 = *(const bf16x8*)(myrep + (3 * 64 + lane) * 16); \
  WAITLDS \
  RPK_H(acc10, 0, R) RPK_H(acc11, 1, R) RPK_H(acc12, 2, R) RPK_H(acc13, 3, R) \
  RPK_H(acc14, 4, R) RPK_H(acc15, 5, R) RPK_H(acc16, 6, R) RPK_H(acc17, 7, R) \
  WAITLDS \
  x10 = *(const bf16x8*)(myrep + (0 * 64 + lane) * 16); \
  x11 = *(const bf16x8*)(myrep + (1 * 64 + lane) * 16); \
  x12 = *(const bf16x8*)(myrep + (2 * 64 + lane) * 16); \
  x13 = *(const bf16x8*)(myrep + (3 * 64 + lane) * 16); \
  WAITLDS

#define LOADX(d0, d1, basep, kk) { \
  float4 a0 = *(const float4*)((basep) + r0 + (kk) * 32); \
  float4 a1 = *(const float4*)((basep) + r0 + (kk) * 32 + 4); \
  float4 b0 = *(const float4*)((basep) + r1 + (kk) * 32); \
  float4 b1 = *(const float4*)((basep) + r1 + (kk) * 32 + 4); \
  d0 = cvt8(a0, a1); d1 = cvt8(b0, b1); }

#define ST(av, mt, nb) { f32x4 v = av; \
  *(float4*)(out + (rowbase + (mt) * 16 + c) * 128 + (nb) * 16 + g * 4) = \
      (float4){v[0], v[1], v[2], v[3]}; }

// 512 threads (8 waves x 32 rows = 256 rows/block), grid 2500.
// LDS 128KB: W 0..96K (Wm1|Wm2 then Wu1|Wu2), repack 96K..128K (4KB/wave).
// 3 barriers total; 2 stage phases; repack is wave-private (no barriers).
// 512-thr block => HW requires <=256 unified regs/wave => 2 waves/SIMD.
__global__ __launch_bounds__(512) void fused_mp(
    const float* __restrict__ hself, const float* __restrict__ hother,
    const bf16_t* __restrict__ wt,
    const float* __restrict__ bm1, const float* __restrict__ bm2,
    const float* __restrict__ bu1, const float* __restrict__ bu2,
    float* __restrict__ out) {
  __shared__ char smem[131072];

  const int tid = threadIdx.x;
  const int lane = tid & 63;
  const int wave = tid >> 6;
  const int c = lane & 15;
  const int g = lane >> 4;

  char* W1 = smem;            // frags 0..63   (Wm1 / Wu1)
  char* W2 = smem + 65536;    // frags 64..95  (Wm2 / Wu2)
  char* myrep = smem + 98304 + wave * 4096;

  const size_t rowbase = (size_t)blockIdx.x * BM + wave * 32;
  const size_t r0 = (rowbase + c) * 128 + g * 8;
  const size_t r1 = (rowbase + 16 + c) * 128 + g * 8;

  // ---- prologue: hs loads, async Wm1+Wm2 DMA (96KB), ho loads ----
  bf16x8 hs00, hs01, hs02, hs03, hs10, hs11, hs12, hs13;
  bf16x8 x00, x01, x02, x03, x10, x11, x12, x13;
  LOADX(hs00, hs10, hself, 0)
  LOADX(hs01, hs11, hself, 1)
  LOADX(hs02, hs12, hself, 2)
  LOADX(hs03, hs13, hself, 3)
  STAGE96(0)
  LOADX(x00, x10, hother, 0)
  LOADX(x01, x11, hother, 1)
  LOADX(x02, x12, hother, 2)
  LOADX(x03, x13, hother, 3)
  VMCNT0
  __syncthreads();  // B0: Wm1+Wm2 staged

  f32x4 acc00, acc01, acc02, acc03, acc04, acc05, acc06, acc07;
  f32x4 acc10, acc11, acc12, acc13, acc14, acc15, acc16, acc17;
  bf16x8 wa0, wa1, wa2, wa3, wa4, wa5, wa6, wa7;

  // ============ GEMM1: h1^T = Wm1^T [hs|ho]^T  (+bm1, relu) ============
  ACCINIT(bm1)
  LDW8(wa, W1, 0)   ROUND(wa, hs00, hs10)
  LDW8(wa, W1, 8)   ROUND(wa, hs01, hs11)
  LDW8(wa, W1, 16)  ROUND(wa, hs02, hs12)
  LDW8(wa, W1, 24)  ROUND(wa, hs03, hs13)
  LDW8(wa, W1, 32)  ROUND(wa, x00, x10)
  LDW8(wa, W1, 40)  ROUND(wa, x01, x11)
  LDW8(wa, W1, 48)  ROUND(wa, x02, x12)
  LDW8(wa, W1, 56)  ROUND(wa, x03, x13)

  REPACK(true)  // x-block = h1 B-frags (wave-local)

  // ============ GEMM2: msg^T = Wm2^T h1^T  (+bm2) ============
  ACCINIT(bm2)
  LDW8(wa, W2, 0)   ROUND(wa, x00, x10)
  LDW8(wa, W2, 8)   ROUND(wa, x01, x11)
  LDW8(wa, W2, 16)  ROUND(wa, x02, x12)
  LDW8(wa, W2, 24)  ROUND(wa, x03, x13)

  REPACK(false)  // x-block = msg B-frags (wave-local)

  __syncthreads();  // B1: all waves done reading Wm1/Wm2
  STAGE96(6144)     // Wu1+Wu2 -> same 96KB
  VMCNT0
  __syncthreads();  // B2: Wu1+Wu2 staged

  // ============ GEMM3: h2^T = Wu1^T [hs|msg]^T  (+bu1, relu) ============
  ACCINIT(bu1)
  LDW8(wa, W1, 0)   ROUND(wa, hs00, hs10)
  LDW8(wa, W1, 8)   ROUND(wa, hs01, hs11)
  LDW8(wa, W1, 16)  ROUND(wa, hs02, hs12)
  LDW8(wa, W1, 24)  ROUND(wa, hs03, hs13)
  LDW8(wa, W1, 32)  ROUND(wa, x00, x10)
  LDW8(wa, W1, 40)  ROUND(wa, x01, x11)
  LDW8(wa, W1, 48)  ROUND(wa, x02, x12)
  LDW8(wa, W1, 56)  ROUND(wa, x03, x13)

  REPACK(true)  // x-block = h2 B-frags (wave-local)

  // ============ GEMM4: out^T = Wu2^T h2^T  (+bu2) ============
  ACCINIT(bu2)
  LDW8(wa, W2, 0)   ROUND(wa, x00, x10)
  LDW8(wa, W2, 8)   ROUND(wa, x01, x11)
  LDW8(wa, W2, 16)  ROUND(wa, x02, x12)
  LDW8(wa, W2, 24)  ROUND(wa, x03, x13)

  ST(acc00, 0, 0) ST(acc01, 0, 1) ST(acc02, 0, 2) ST(acc03, 0, 3)
  ST(acc04, 0, 4) ST(acc05, 0, 5) ST(acc06, 0, 6) ST(acc07, 0, 7)
  ST(acc10, 1, 0) ST(acc11, 1, 1) ST(acc12, 1, 2) ST(acc13, 1, 3)
  ST(acc14, 1, 4) ST(acc15, 1, 5) ST(acc16, 1, 6) ST(acc17, 1, 7)
}

extern "C" void kernel_launch(void* const* d_in, const int* in_sizes, int n_in,
                              void* d_out, int out_size, void* d_ws, size_t ws_size,
                              hipStream_t stream) {
  const float* hself  = (const float*)d_in[0];
  const float* hother = (const float*)d_in[1];
  const float* Wm1 = (const float*)d_in[2];
  const float* bm1 = (const float*)d_in[3];
  const float* Wm2 = (const float*)d_in[4];
  const float* bm2 = (const float*)d_in[5];
  const float* Wu1 = (const float*)d_in[6];
  const float* bu1 = (const float*)d_in[7];
  const float* Wu2 = (const float*)d_in[8];
  const float* bu2 = (const float*)d_in[9];
  float* out = (float*)d_out;
  bf16_t* wt = (bf16_t*)d_ws;  // 196608 B of fragment-ordered bf16 weights

  prep_weights<<<48, 256, 0, stream>>>(Wm1, Wm2, Wu1, Wu2, wt);
  fused_mp<<<E_ROWS / BM, 512, 0, stream>>>(hself, hother, wt,
                                            bm1, bm2, bu1, bu2, out);
}